// Round 6
// baseline (83.942 us; speedup 1.0000x reference)
//
#include <hip/hip_runtime.h>
#include <math.h>
#include <stdint.h>

// PedestrianDetector v10: copy-kernel-identical global pattern, reg-staged,
// single 64KB LDS buffer (static-LDS-safe after v9's 128KB launch death).
//
// Tested variable: global WALK ORDER. v4-v7 all walked 16K row-streams in
// column-lockstep (8KB stride between consecutive accesses machine-wide) and
// all landed at 40us / 3.35 TB/s. v10 makes each wave walk 4 rows as pure
// sequential streams: one global_load_dwordx4 = one row's full 1KB contiguous
// span (64 lanes x 16B), chunks advance sequentially along the row -> the
// aggregate traffic is indistinguishable from the 6.3 TB/s float4-copy ubench.
//
// Pipeline (T14 issue-early/write-late, registers replace the 2nd LDS buffer):
//   per chunk: [issue loads(c+1) -> 16 VGPR] [compute(c) from LDS]
//              [barrier] [regs -> LDS, XOR-swizzled] [barrier]
// Compiler manages all waitcnts (no inline asm): the ds_write's data
// dependence forces the vmcnt wait; __syncthreads() orders LDS reuse.
// Compute/reduce/epilogue: v6 verbatim (lane=row, wave-uniform d -> scalar-W
// SGPR path, stride-15 partials, stable top-3, packed outputs).

#define DCOLS 2048
#define RPB   64              // rows per block
#define NW    16              // waves per block (1024 threads)
#define CCH   256             // chunk width in d (1KB per row per chunk)
#define NCH   (DCOLS / CCH)   // 8 chunks
#define TILEF (RPB * CCH)     // 16384 floats = 65,536 B (static-LDS max)
#define PSTR  15              // partials row stride (odd -> conflict-free)

__global__ __launch_bounds__(1024, 4)
void ped_det_kernel(const float* __restrict__ feat,
                    const float* __restrict__ Wb,   // [2048][12]
                    const float* __restrict__ bb,   // [12]
                    const float* __restrict__ Wc,   // [2048][3]
                    const float* __restrict__ bc,   // [3]
                    float* __restrict__ out,
                    int nrows)
{
    __shared__ __align__(16) float buf[TILEF];   // 65,536 B, single buffer
    float* P = &buf[0];   // [16][64][15] partials (61,440 B) alias, after loop
    float* S = P;         // [64][16] biased sums alias, behind further barrier

    const int t    = threadIdx.x;
    const int lane = t & 63;
    const int w    = t >> 6;
    const int wu   = __builtin_amdgcn_readfirstlane(w);  // wave-uniform -> scalar W

    const int rowBase = blockIdx.x * RPB;
    const float* fbase = feat + (size_t)rowBase * DCOLS;

    float acc[15];
#pragma unroll
    for (int j = 0; j < 15; ++j) acc[j] = 0.0f;

    // staged chunk lives in registers: wave wu owns rows wu*4..wu*4+3,
    // lane l carries content slot l (d = c*256 + l*4 .. +3) of each row.
    float4 rg[4];

    auto LOADC = [&](int c) {
#pragma unroll
        for (int i = 0; i < 4; ++i) {
            const int r = wu * 4 + i;
            rg[i] = *(const float4*)(fbase + (size_t)r * DCOLS
                                     + c * CCH + (lane << 2));
        }
    };
    // regs -> LDS, slot XOR-swizzle (rule 21): row r content slot l stored at
    // physical slot l^(r&7); read applies the same XOR (involution).
    auto DSWRITE = [&]() {
#pragma unroll
        for (int i = 0; i < 4; ++i) {
            const int r = wu * 4 + i;
            *(float4*)(&buf[(size_t)r * CCH + ((lane ^ (r & 7)) << 2)]) = rg[i];
        }
    };

    // prologue: fill chunk 0
    LOADC(0);
    DSWRITE();          // compiler inserts the vmcnt wait (data dependence)
    __syncthreads();

    for (int c = 0; c < NCH; ++c) {
        if (c + 1 < NCH) LOADC(c + 1);   // issue early: hides under compute(c)

        // compute chunk c: wave wu consumes content slots s = wu*4+q,
        // i.e. wave-uniform d-slice [c*256 + wu*16, +16); row = lane.
#pragma unroll
        for (int q = 0; q < 4; ++q) {
            const int s = wu * 4 + q;
            const float4 f = *(const float4*)(&buf[(size_t)lane * CCH
                                              + ((s ^ (lane & 7)) << 2)]);
            const int du = c * CCH + wu * 16 + q * 4;        // wave-uniform
            const float* __restrict__ wbp = Wb + (size_t)du * 12;
            const float* __restrict__ wcp = Wc + (size_t)du * 3;
            const float fv[4] = { f.x, f.y, f.z, f.w };
#pragma unroll
            for (int jj = 0; jj < 4; ++jj) {
                const float v = fv[jj];
                acc[0]  += v * wbp[jj * 12 + 0];
                acc[1]  += v * wbp[jj * 12 + 1];
                acc[2]  += v * wbp[jj * 12 + 2];
                acc[3]  += v * wbp[jj * 12 + 3];
                acc[4]  += v * wbp[jj * 12 + 4];
                acc[5]  += v * wbp[jj * 12 + 5];
                acc[6]  += v * wbp[jj * 12 + 6];
                acc[7]  += v * wbp[jj * 12 + 7];
                acc[8]  += v * wbp[jj * 12 + 8];
                acc[9]  += v * wbp[jj * 12 + 9];
                acc[10] += v * wbp[jj * 12 + 10];
                acc[11] += v * wbp[jj * 12 + 11];
                acc[12] += v * wcp[jj * 3 + 0];
                acc[13] += v * wcp[jj * 3 + 1];
                acc[14] += v * wcp[jj * 3 + 2];
            }
        }

        __syncthreads();                 // all waves done reading chunk c
        if (c + 1 < NCH) {
            DSWRITE();                   // land chunk c+1 (vmcnt wait auto)
            __syncthreads();             // writes visible before next compute
        }
    }

    // ---- write per-wave partials (stride 15, odd -> <=2-way aliasing = free)
    __syncthreads();                     // compute done in all waves before alias
    {
        float* pp = &P[(wu * RPB + lane) * PSTR];
#pragma unroll
        for (int j = 0; j < 15; ++j) pp[j] = acc[j];
    }
    __syncthreads();

    // ---- reduce 16 wave-partials per (row, j), add bias -> register s
    float sval = 0.0f;
    int rl = 0, jj = 0;
    if (t < RPB * 15) {                 // u = t = rl*15 + j (consecutive -> conflict-free)
        rl = t / 15;
        jj = t % 15;
        float s = 0.0f;
#pragma unroll
        for (int w2 = 0; w2 < NW; ++w2)
            s += P[(w2 * RPB + rl) * PSTR + jj];
        s += (jj < 12) ? bb[jj] : bc[jj - 12];
        sval = s;
    }
    __syncthreads();                    // all P reads done before S (alias) is written

    if (t < RPB * 15)
        S[rl * 16 + jj] = sval;
    __syncthreads();

    // ---- epilogue: sigmoid, stable top-3 (ties -> lower index), threshold, store
    if (t < RPB) {
        const int r2 = t;
        float box[12];
#pragma unroll
        for (int j = 0; j < 12; ++j) box[j] = S[r2 * 16 + j];
        float conf[3];
#pragma unroll
        for (int a = 0; a < 3; ++a)
            conf[a] = 1.0f / (1.0f + __expf(-S[r2 * 16 + 12 + a]));

        int i0 = 0; float m0 = conf[0];
        if (conf[1] > m0) { i0 = 1; m0 = conf[1]; }
        if (conf[2] > m0) { i0 = 2; m0 = conf[2]; }
        const int ra = (i0 == 0) ? 1 : 0;
        const int rb = (i0 == 2) ? 1 : 2;
        int i1, i2;
        if (conf[rb] > conf[ra]) { i1 = rb; i2 = ra; }
        else                     { i1 = ra; i2 = rb; }
        const int idx[3] = { i0, i1, i2 };

        const int ro = blockIdx.x * RPB + r2;
        float* boxout  = out + (size_t)ro * 12;
        float* confout = out + (size_t)nrows * 12 + (size_t)ro * 3;
        float* valout  = out + (size_t)nrows * 15 + (size_t)ro * 3;
#pragma unroll
        for (int sl = 0; sl < 3; ++sl) {
            const int   a   = idx[sl];
            const float cv  = conf[a];
            const bool  vld = cv > 0.5f;
            float4 bx;
            bx.x = vld ? box[a * 4 + 0] : 0.0f;
            bx.y = vld ? box[a * 4 + 1] : 0.0f;
            bx.z = vld ? box[a * 4 + 2] : 0.0f;
            bx.w = vld ? box[a * 4 + 3] : 0.0f;
            *(float4*)(boxout + sl * 4) = bx;
            confout[sl] = cv;
            valout[sl]  = vld ? 1.0f : 0.0f;
        }
    }
}

extern "C" void kernel_launch(void* const* d_in, const int* in_sizes, int n_in,
                              void* d_out, int out_size, void* d_ws, size_t ws_size,
                              hipStream_t stream) {
    const float* feat = (const float*)d_in[0];
    const float* Wb   = (const float*)d_in[1];
    const float* bb   = (const float*)d_in[2];
    const float* Wc   = (const float*)d_in[3];
    const float* bc   = (const float*)d_in[4];
    float* out = (float*)d_out;

    const int nrows   = in_sizes[0] / DCOLS;   // 16384
    const int nblocks = nrows / RPB;           // 256 -> 1 block/CU

    ped_det_kernel<<<dim3(nblocks), dim3(1024), 0, stream>>>(
        feat, Wb, bb, Wc, bc, out, nrows);
}

// Round 7
// 59.304 us; speedup vs baseline: 1.4154x; 1.4154x over previous
//
#include <hip/hip_runtime.h>
#include <math.h>
#include <stdint.h>

// PedestrianDetector v11 — DIAGNOSTIC ROUND (two dispatches):
//  1) probe_kernel: rule-10 known-good comparator. Grid-stride float4 read of
//     the exact feature buffer in the m13-ubench shape (2048 blk x 256 thr,
//     8MB stride, 32 streams/CU) -> per-thread sums to d_ws (not DCE-able).
//     Its rocprof dur/hbm_gbps is the ground-truth read ceiling for this data.
//  2) ped_det_kernel: v7 verbatim (best clean 40.0us) with ONE variable
//     changed: global_load_lds aux = NT (streaming, gfx940+ CPol bit1) --
//     the cache fill policy is the single knob all six prior variants shared.
// Interpretation matrix:
//   probe fast + main fast  -> NT is the lever, keep it, drop probe next round
//   probe fast + main ~40   -> consume-side coupling; restructure next round
//   probe ~40               -> buffer-level ceiling; declare roofline w/ evidence

#define DCOLS 2048
#define RPB   64
#define NW    16
#define CCH   64
#define NCH   (DCOLS / CCH)
#define NBUF  4
#define TILEF (RPB * CCH)
#define PSTR  15

// ---------------- probe: ubench-identical reader ----------------
__global__ __launch_bounds__(256)
void probe_kernel(const float4* __restrict__ f, float* __restrict__ ws, int n4)
{
    const int tid    = blockIdx.x * 256 + threadIdx.x;
    const int stride = gridDim.x * 256;
    float s = 0.0f;
    for (int i = tid; i < n4; i += stride) {
        const float4 v = f[i];
        s += v.x + v.y + v.z + v.w;
    }
    ws[tid] = s;   // defeats DCE; 2MB to workspace, ~0.3us
}

// ---------------- main: v7 + NT staging ----------------
__global__ __launch_bounds__(1024, 4)
void ped_det_kernel(const float* __restrict__ feat,
                    const float* __restrict__ Wb,   // [2048][12]
                    const float* __restrict__ bb,   // [12]
                    const float* __restrict__ Wc,   // [2048][3]
                    const float* __restrict__ bc,   // [3]
                    float* __restrict__ out,
                    int nrows)
{
    __shared__ __align__(16) float lds[NBUF][TILEF];   // 65,536 B
    float* P = &lds[0][0];
    float* S = P;

    const int t    = threadIdx.x;
    const int lane = t & 63;
    const int w    = t >> 6;
    const int wu   = __builtin_amdgcn_readfirstlane(w);

    const int rowBase = blockIdx.x * RPB;
    const int bph = (int)(blockIdx.x) & (NCH - 1);

    const int rsub = lane >> 4;
    const int su   = lane & 15;
    const int rst  = wu * 4 + rsub;
    const size_t gofs = (size_t)rst * DCOLS + ((su ^ (rst & 7)) << 2);
    const float* fbase = feat + (size_t)rowBase * DCOLS;

    auto STAGE = [&](int c, int p) {
        const int ca = (c + bph) & (NCH - 1);
        const float* g = fbase + gofs + ca * CCH;
        const float* l = &lds[p][wu * 4 * CCH];
        // aux=2: NT (non-temporal) streaming read — the ONE changed variable
        __builtin_amdgcn_global_load_lds(
            (const __attribute__((address_space(1))) void*)g,
            (__attribute__((address_space(3))) void*)l, 16, 0, 2);
    };

    const int roff = lane * CCH + ((wu ^ (lane & 7)) << 2);

    float acc[15];
#pragma unroll
    for (int j = 0; j < 15; ++j) acc[j] = 0.0f;

    STAGE(0, 0);
    STAGE(1, 1);
    STAGE(2, 2);

    for (int c = 0; c < NCH; ++c) {
        if (c + 3 < NCH) STAGE(c + 3, (c + 3) & (NBUF - 1));

        const int rem = NCH - 1 - c;
        if (rem >= 3)      asm volatile("s_waitcnt vmcnt(3)" ::: "memory");
        else if (rem == 2) asm volatile("s_waitcnt vmcnt(2)" ::: "memory");
        else if (rem == 1) asm volatile("s_waitcnt vmcnt(1)" ::: "memory");
        else               asm volatile("s_waitcnt vmcnt(0)" ::: "memory");
        asm volatile("s_barrier" ::: "memory");

        const float* buf = &lds[c & (NBUF - 1)][0];
        const float4 f = *(const float4*)(buf + roff);

        const int ca = (c + bph) & (NCH - 1);
        const int du = ca * CCH + wu * 4;
        const float* __restrict__ wbp = Wb + (size_t)du * 12;
        const float* __restrict__ wcp = Wc + (size_t)du * 3;
        const float fv[4] = { f.x, f.y, f.z, f.w };
#pragma unroll
        for (int j = 0; j < 4; ++j) {
            const float v = fv[j];
            acc[0]  += v * wbp[j * 12 + 0];
            acc[1]  += v * wbp[j * 12 + 1];
            acc[2]  += v * wbp[j * 12 + 2];
            acc[3]  += v * wbp[j * 12 + 3];
            acc[4]  += v * wbp[j * 12 + 4];
            acc[5]  += v * wbp[j * 12 + 5];
            acc[6]  += v * wbp[j * 12 + 6];
            acc[7]  += v * wbp[j * 12 + 7];
            acc[8]  += v * wbp[j * 12 + 8];
            acc[9]  += v * wbp[j * 12 + 9];
            acc[10] += v * wbp[j * 12 + 10];
            acc[11] += v * wbp[j * 12 + 11];
            acc[12] += v * wcp[j * 3 + 0];
            acc[13] += v * wcp[j * 3 + 1];
            acc[14] += v * wcp[j * 3 + 2];
        }

        asm volatile("s_waitcnt lgkmcnt(0)" ::: "memory");
        asm volatile("s_barrier" ::: "memory");
    }

    {
        float* pp = &P[(wu * RPB + lane) * PSTR];
#pragma unroll
        for (int j = 0; j < 15; ++j) pp[j] = acc[j];
    }
    __syncthreads();

    float sval = 0.0f;
    int rl = 0, jj = 0;
    if (t < RPB * 15) {
        rl = t / 15;
        jj = t % 15;
        float s = 0.0f;
#pragma unroll
        for (int w2 = 0; w2 < NW; ++w2)
            s += P[(w2 * RPB + rl) * PSTR + jj];
        s += (jj < 12) ? bb[jj] : bc[jj - 12];
        sval = s;
    }
    __syncthreads();

    if (t < RPB * 15)
        S[rl * 16 + jj] = sval;
    __syncthreads();

    if (t < RPB) {
        const int r2 = t;
        float box[12];
#pragma unroll
        for (int j = 0; j < 12; ++j) box[j] = S[r2 * 16 + j];
        float conf[3];
#pragma unroll
        for (int a = 0; a < 3; ++a)
            conf[a] = 1.0f / (1.0f + __expf(-S[r2 * 16 + 12 + a]));

        int i0 = 0; float m0 = conf[0];
        if (conf[1] > m0) { i0 = 1; m0 = conf[1]; }
        if (conf[2] > m0) { i0 = 2; m0 = conf[2]; }
        const int ra = (i0 == 0) ? 1 : 0;
        const int rb = (i0 == 2) ? 1 : 2;
        int i1, i2;
        if (conf[rb] > conf[ra]) { i1 = rb; i2 = ra; }
        else                     { i1 = ra; i2 = rb; }
        const int idx[3] = { i0, i1, i2 };

        const int ro = blockIdx.x * RPB + r2;
        float* boxout  = out + (size_t)ro * 12;
        float* confout = out + (size_t)nrows * 12 + (size_t)ro * 3;
        float* valout  = out + (size_t)nrows * 15 + (size_t)ro * 3;
#pragma unroll
        for (int sl = 0; sl < 3; ++sl) {
            const int   a   = idx[sl];
            const float cv  = conf[a];
            const bool  vld = cv > 0.5f;
            float4 bx;
            bx.x = vld ? box[a * 4 + 0] : 0.0f;
            bx.y = vld ? box[a * 4 + 1] : 0.0f;
            bx.z = vld ? box[a * 4 + 2] : 0.0f;
            bx.w = vld ? box[a * 4 + 3] : 0.0f;
            *(float4*)(boxout + sl * 4) = bx;
            confout[sl] = cv;
            valout[sl]  = vld ? 1.0f : 0.0f;
        }
    }
}

extern "C" void kernel_launch(void* const* d_in, const int* in_sizes, int n_in,
                              void* d_out, int out_size, void* d_ws, size_t ws_size,
                              hipStream_t stream) {
    const float* feat = (const float*)d_in[0];
    const float* Wb   = (const float*)d_in[1];
    const float* bb   = (const float*)d_in[2];
    const float* Wc   = (const float*)d_in[3];
    const float* bc   = (const float*)d_in[4];
    float* out = (float*)d_out;

    const int nrows   = in_sizes[0] / DCOLS;   // 16384
    const int nblocks = nrows / RPB;           // 256 -> 1 block/CU

    // 1) ground-truth comparator: ubench-shaped read of the same buffer
    if (ws_size >= (size_t)2048 * 256 * sizeof(float)) {
        const int n4 = nrows * (DCOLS / 4);    // 8,388,608 float4s
        probe_kernel<<<dim3(2048), dim3(256), 0, stream>>>(
            (const float4*)feat, (float*)d_ws, n4);
    }

    // 2) the real kernel (v7 + NT staging)
    ped_det_kernel<<<dim3(nblocks), dim3(1024), 0, stream>>>(
        feat, Wb, bb, Wc, bc, out, nrows);
}

// Round 8
// 41.115 us; speedup vs baseline: 2.0416x; 1.4424x over previous
//
#include <hip/hip_runtime.h>
#include <math.h>
#include <stdint.h>

// PedestrianDetector v13 = v9 (1KB-per-row DRAM granule) with DYNAMIC 128KB LDS.
//
// Evidence chain: v11's rule-10 probe read this exact buffer at ~6.3 TB/s with
// 1KB-per-wave-step coalesced loads; v4 (64B grain) and v5/v6/v7 (256B grain)
// all sit at 3.35 TB/s regardless of structure -> stream-granule hypothesis is
// the only survivor. v9 tested 1KB granules but used 128KB STATIC __shared__
// (launch death). v13 uses extern __shared__ + hipFuncSetAttribute (m201
// precedent: 128KiB dynamic LDS works on gfx950). Fallback: v7's verified
// 64KB kernel if the attribute call fails.
//
// Structure (v6-verbatim except chunk width): 256 blocks x 1024 threads,
// 1 block/CU, 64 rows/block, 8 chunks of 256 d. Buffer = 64 rows x 1KB =
// 64KB, double-buffered (131,072B dynamic). Stage: wave wu stages rows
// wu*4..wu*4+3, ONE global_load_lds dwordx4 per row = 64 lanes x 16B = the
// row's full 1KB contiguous span. Source slot = lane^(r&7) (16B-slot XOR
// within 128B groups -> coalescing preserved), LDS dest linear, read applies
// the same XOR (rule 21 involution). Counted vmcnt(4): chunk c+1's 4 stage
// instrs stay in flight while computing c. Scalar-W FMA loop, stride-15
// reduce, stable top-3 epilogue: v6/v7 verbatim (harness-verified).

#define DCOLS 2048
#define RPB   64              // rows per block
#define NW    16              // waves per block (1024 threads)
#define PSTR  15              // partials row stride (odd -> conflict-free)

// ---- v13 main: 1KB granule, dynamic 128KB LDS ----
#define CCH9  256             // chunk width in d (1KB per row per chunk)
#define NCH9  (DCOLS / CCH9)  // 8 chunks
#define TILE9 (RPB * CCH9)    // 16384 floats = 64KB per buffer

__global__ __launch_bounds__(1024, 4)
void ped_det_kernel_dyn(const float* __restrict__ feat,
                        const float* __restrict__ Wb,   // [2048][12]
                        const float* __restrict__ bb,   // [12]
                        const float* __restrict__ Wc,   // [2048][3]
                        const float* __restrict__ bc,   // [3]
                        float* __restrict__ out,
                        int nrows)
{
    extern __shared__ __align__(16) float lds[];   // [2][TILE9] = 131,072 B
    float* P = &lds[0];   // [16][64][15] partials (61,440 B) alias, after loop
    float* S = P;         // [64][16] biased sums alias, behind further barrier

    const int t    = threadIdx.x;
    const int lane = t & 63;
    const int w    = t >> 6;
    const int wu   = __builtin_amdgcn_readfirstlane(w);  // wave-uniform -> scalar W

    const int rowBase = blockIdx.x * RPB;
    const float* fbase = feat + (size_t)rowBase * DCOLS;

    // stage: wave wu stages rows wu*4..wu*4+3; one instr = one row's full 1KB
    // span (64 lanes x 16B). Dest slot = lane (linear); source slot =
    // lane ^ (r&7): 16B-slot XOR within 128B groups (coalescing preserved).
    auto STAGE = [&](int c, int p) {
#pragma unroll
        for (int i = 0; i < 4; ++i) {
            const int r = wu * 4 + i;
            const float* g = fbase + (size_t)r * DCOLS + c * CCH9
                           + ((lane ^ (r & 7)) << 2);
            const float* l = &lds[(size_t)p * TILE9 + r * CCH9];  // wave-uniform
            __builtin_amdgcn_global_load_lds(
                (const __attribute__((address_space(1))) void*)g,
                (__attribute__((address_space(3))) void*)l, 16, 0, 0);
        }
    };

    float acc[15];
#pragma unroll
    for (int j = 0; j < 15; ++j) acc[j] = 0.0f;

    STAGE(0, 0);

    for (int c = 0; c < NCH9; ++c) {
        if (c + 1 < NCH9) {
            STAGE(c + 1, (c + 1) & 1);
            asm volatile("s_waitcnt vmcnt(4)" ::: "memory");  // retire chunk c only
        } else {
            asm volatile("s_waitcnt vmcnt(0)" ::: "memory");
        }
        asm volatile("s_barrier" ::: "memory");   // all rows of chunk c resident

        const float* buf = &lds[(size_t)(c & 1) * TILE9];
        // wave wu consumes d-slice [wu*16, wu*16+16): 4 x float4 at content
        // slots s = wu*4+q (wave-uniform), row = lane, swizzled read.
#pragma unroll
        for (int q = 0; q < 4; ++q) {
            const int s = wu * 4 + q;
            const float4 f = *(const float4*)(buf + (size_t)lane * CCH9
                                              + ((s ^ (lane & 7)) << 2));
            const int du = c * CCH9 + wu * 16 + q * 4;       // wave-uniform d
            const float* __restrict__ wbp = Wb + (size_t)du * 12;
            const float* __restrict__ wcp = Wc + (size_t)du * 3;
            const float fv[4] = { f.x, f.y, f.z, f.w };
#pragma unroll
            for (int jj = 0; jj < 4; ++jj) {
                const float v = fv[jj];
                acc[0]  += v * wbp[jj * 12 + 0];
                acc[1]  += v * wbp[jj * 12 + 1];
                acc[2]  += v * wbp[jj * 12 + 2];
                acc[3]  += v * wbp[jj * 12 + 3];
                acc[4]  += v * wbp[jj * 12 + 4];
                acc[5]  += v * wbp[jj * 12 + 5];
                acc[6]  += v * wbp[jj * 12 + 6];
                acc[7]  += v * wbp[jj * 12 + 7];
                acc[8]  += v * wbp[jj * 12 + 8];
                acc[9]  += v * wbp[jj * 12 + 9];
                acc[10] += v * wbp[jj * 12 + 10];
                acc[11] += v * wbp[jj * 12 + 11];
                acc[12] += v * wcp[jj * 3 + 0];
                acc[13] += v * wcp[jj * 3 + 1];
                acc[14] += v * wcp[jj * 3 + 2];
            }
        }

        asm volatile("s_waitcnt lgkmcnt(0)" ::: "memory");
        asm volatile("s_barrier" ::: "memory");
    }

    // ---- reduce + epilogue (v6/v7 verbatim) ----
    {
        float* pp = &P[(wu * RPB + lane) * PSTR];
#pragma unroll
        for (int j = 0; j < 15; ++j) pp[j] = acc[j];
    }
    __syncthreads();

    float sval = 0.0f;
    int rl = 0, jj = 0;
    if (t < RPB * 15) {
        rl = t / 15;
        jj = t % 15;
        float s = 0.0f;
#pragma unroll
        for (int w2 = 0; w2 < NW; ++w2)
            s += P[(w2 * RPB + rl) * PSTR + jj];
        s += (jj < 12) ? bb[jj] : bc[jj - 12];
        sval = s;
    }
    __syncthreads();

    if (t < RPB * 15)
        S[rl * 16 + jj] = sval;
    __syncthreads();

    if (t < RPB) {
        const int r2 = t;
        float box[12];
#pragma unroll
        for (int j = 0; j < 12; ++j) box[j] = S[r2 * 16 + j];
        float conf[3];
#pragma unroll
        for (int a = 0; a < 3; ++a)
            conf[a] = 1.0f / (1.0f + __expf(-S[r2 * 16 + 12 + a]));

        int i0 = 0; float m0 = conf[0];
        if (conf[1] > m0) { i0 = 1; m0 = conf[1]; }
        if (conf[2] > m0) { i0 = 2; m0 = conf[2]; }
        const int ra = (i0 == 0) ? 1 : 0;
        const int rb = (i0 == 2) ? 1 : 2;
        int i1, i2;
        if (conf[rb] > conf[ra]) { i1 = rb; i2 = ra; }
        else                     { i1 = ra; i2 = rb; }
        const int idx[3] = { i0, i1, i2 };

        const int ro = blockIdx.x * RPB + r2;
        float* boxout  = out + (size_t)ro * 12;
        float* confout = out + (size_t)nrows * 12 + (size_t)ro * 3;
        float* valout  = out + (size_t)nrows * 15 + (size_t)ro * 3;
#pragma unroll
        for (int sl = 0; sl < 3; ++sl) {
            const int   a   = idx[sl];
            const float cv  = conf[a];
            const bool  vld = cv > 0.5f;
            float4 bx;
            bx.x = vld ? box[a * 4 + 0] : 0.0f;
            bx.y = vld ? box[a * 4 + 1] : 0.0f;
            bx.z = vld ? box[a * 4 + 2] : 0.0f;
            bx.w = vld ? box[a * 4 + 3] : 0.0f;
            *(float4*)(boxout + sl * 4) = bx;
            confout[sl] = cv;
            valout[sl]  = vld ? 1.0f : 0.0f;
        }
    }
}

// ---- fallback: v7 verbatim (verified 40.0us, 64KB static LDS) ----
#define CCH7  64
#define NCH7  (DCOLS / CCH7)
#define NBUF7 4
#define TILE7 (RPB * CCH7)

__global__ __launch_bounds__(1024, 4)
void ped_det_kernel_64(const float* __restrict__ feat,
                       const float* __restrict__ Wb,
                       const float* __restrict__ bb,
                       const float* __restrict__ Wc,
                       const float* __restrict__ bc,
                       float* __restrict__ out,
                       int nrows)
{
    __shared__ __align__(16) float lds[NBUF7][TILE7];
    float* P = &lds[0][0];
    float* S = P;

    const int t    = threadIdx.x;
    const int lane = t & 63;
    const int w    = t >> 6;
    const int wu   = __builtin_amdgcn_readfirstlane(w);

    const int rowBase = blockIdx.x * RPB;
    const int bph = (int)(blockIdx.x) & (NCH7 - 1);

    const int rsub = lane >> 4;
    const int su   = lane & 15;
    const int rst  = wu * 4 + rsub;
    const size_t gofs = (size_t)rst * DCOLS + ((su ^ (rst & 7)) << 2);
    const float* fbase = feat + (size_t)rowBase * DCOLS;

    auto STAGE = [&](int c, int p) {
        const int ca = (c + bph) & (NCH7 - 1);
        const float* g = fbase + gofs + ca * CCH7;
        const float* l = &lds[p][wu * 4 * CCH7];
        __builtin_amdgcn_global_load_lds(
            (const __attribute__((address_space(1))) void*)g,
            (__attribute__((address_space(3))) void*)l, 16, 0, 0);
    };

    const int roff = lane * CCH7 + ((wu ^ (lane & 7)) << 2);

    float acc[15];
#pragma unroll
    for (int j = 0; j < 15; ++j) acc[j] = 0.0f;

    STAGE(0, 0);
    STAGE(1, 1);
    STAGE(2, 2);

    for (int c = 0; c < NCH7; ++c) {
        if (c + 3 < NCH7) STAGE(c + 3, (c + 3) & (NBUF7 - 1));

        const int rem = NCH7 - 1 - c;
        if (rem >= 3)      asm volatile("s_waitcnt vmcnt(3)" ::: "memory");
        else if (rem == 2) asm volatile("s_waitcnt vmcnt(2)" ::: "memory");
        else if (rem == 1) asm volatile("s_waitcnt vmcnt(1)" ::: "memory");
        else               asm volatile("s_waitcnt vmcnt(0)" ::: "memory");
        asm volatile("s_barrier" ::: "memory");

        const float* buf = &lds[c & (NBUF7 - 1)][0];
        const float4 f = *(const float4*)(buf + roff);

        const int ca = (c + bph) & (NCH7 - 1);
        const int du = ca * CCH7 + wu * 4;
        const float* __restrict__ wbp = Wb + (size_t)du * 12;
        const float* __restrict__ wcp = Wc + (size_t)du * 3;
        const float fv[4] = { f.x, f.y, f.z, f.w };
#pragma unroll
        for (int j = 0; j < 4; ++j) {
            const float v = fv[j];
            acc[0]  += v * wbp[j * 12 + 0];
            acc[1]  += v * wbp[j * 12 + 1];
            acc[2]  += v * wbp[j * 12 + 2];
            acc[3]  += v * wbp[j * 12 + 3];
            acc[4]  += v * wbp[j * 12 + 4];
            acc[5]  += v * wbp[j * 12 + 5];
            acc[6]  += v * wbp[j * 12 + 6];
            acc[7]  += v * wbp[j * 12 + 7];
            acc[8]  += v * wbp[j * 12 + 8];
            acc[9]  += v * wbp[j * 12 + 9];
            acc[10] += v * wbp[j * 12 + 10];
            acc[11] += v * wbp[j * 12 + 11];
            acc[12] += v * wcp[j * 3 + 0];
            acc[13] += v * wcp[j * 3 + 1];
            acc[14] += v * wcp[j * 3 + 2];
        }

        asm volatile("s_waitcnt lgkmcnt(0)" ::: "memory");
        asm volatile("s_barrier" ::: "memory");
    }

    {
        float* pp = &P[(wu * RPB + lane) * PSTR];
#pragma unroll
        for (int j = 0; j < 15; ++j) pp[j] = acc[j];
    }
    __syncthreads();

    float sval = 0.0f;
    int rl = 0, jj = 0;
    if (t < RPB * 15) {
        rl = t / 15;
        jj = t % 15;
        float s = 0.0f;
#pragma unroll
        for (int w2 = 0; w2 < NW; ++w2)
            s += P[(w2 * RPB + rl) * PSTR + jj];
        s += (jj < 12) ? bb[jj] : bc[jj - 12];
        sval = s;
    }
    __syncthreads();

    if (t < RPB * 15)
        S[rl * 16 + jj] = sval;
    __syncthreads();

    if (t < RPB) {
        const int r2 = t;
        float box[12];
#pragma unroll
        for (int j = 0; j < 12; ++j) box[j] = S[r2 * 16 + j];
        float conf[3];
#pragma unroll
        for (int a = 0; a < 3; ++a)
            conf[a] = 1.0f / (1.0f + __expf(-S[r2 * 16 + 12 + a]));

        int i0 = 0; float m0 = conf[0];
        if (conf[1] > m0) { i0 = 1; m0 = conf[1]; }
        if (conf[2] > m0) { i0 = 2; m0 = conf[2]; }
        const int ra = (i0 == 0) ? 1 : 0;
        const int rb = (i0 == 2) ? 1 : 2;
        int i1, i2;
        if (conf[rb] > conf[ra]) { i1 = rb; i2 = ra; }
        else                     { i1 = ra; i2 = rb; }
        const int idx[3] = { i0, i1, i2 };

        const int ro = blockIdx.x * RPB + r2;
        float* boxout  = out + (size_t)ro * 12;
        float* confout = out + (size_t)nrows * 12 + (size_t)ro * 3;
        float* valout  = out + (size_t)nrows * 15 + (size_t)ro * 3;
#pragma unroll
        for (int sl = 0; sl < 3; ++sl) {
            const int   a   = idx[sl];
            const float cv  = conf[a];
            const bool  vld = cv > 0.5f;
            float4 bx;
            bx.x = vld ? box[a * 4 + 0] : 0.0f;
            bx.y = vld ? box[a * 4 + 1] : 0.0f;
            bx.z = vld ? box[a * 4 + 2] : 0.0f;
            bx.w = vld ? box[a * 4 + 3] : 0.0f;
            *(float4*)(boxout + sl * 4) = bx;
            confout[sl] = cv;
            valout[sl]  = vld ? 1.0f : 0.0f;
        }
    }
}

extern "C" void kernel_launch(void* const* d_in, const int* in_sizes, int n_in,
                              void* d_out, int out_size, void* d_ws, size_t ws_size,
                              hipStream_t stream) {
    const float* feat = (const float*)d_in[0];
    const float* Wb   = (const float*)d_in[1];
    const float* bb   = (const float*)d_in[2];
    const float* Wc   = (const float*)d_in[3];
    const float* bc   = (const float*)d_in[4];
    float* out = (float*)d_out;

    const int nrows   = in_sizes[0] / DCOLS;   // 16384
    const int nblocks = nrows / RPB;           // 256 -> 1 block/CU

    static int dyn_ok = -1;   // one-time attribute setup (host-side, capture-safe)
    if (dyn_ok < 0) {
        hipError_t e = hipFuncSetAttribute(
            (const void*)ped_det_kernel_dyn,
            hipFuncAttributeMaxDynamicSharedMemorySize, 2 * TILE9 * 4);
        dyn_ok = (e == hipSuccess) ? 1 : 0;
    }

    if (dyn_ok == 1) {
        ped_det_kernel_dyn<<<dim3(nblocks), dim3(1024), 2 * TILE9 * 4, stream>>>(
            feat, Wb, bb, Wc, bc, out, nrows);
    } else {
        ped_det_kernel_64<<<dim3(nblocks), dim3(1024), 0, stream>>>(
            feat, Wb, bb, Wc, bc, out, nrows);
    }
}